// Round 1
// baseline (1005.637 us; speedup 1.0000x reference)
//
#include <hip/hip_runtime.h>
#include <math.h>

#define BATCH 16
#define NCLS 20
#define TOPK 100
#define NPRE 1000
#define NTOT 2400
#define NBINS 8

// ---- order-preserving float->uint map (ascending) ----
__device__ __forceinline__ unsigned int orderable(float x) {
    unsigned int u = __float_as_uint(x);
    return (u & 0x80000000u) ? ~u : (u | 0x80000000u);
}

// ============================================================
// Kernel 1: per (batch, level in {0,1}) exact top-1000 select
// by max class logit (monotone proxy for max sigmoid score).
// ============================================================
__global__ __launch_bounds__(256) void select_topk_kernel(
        const float* __restrict__ cls0, const float* __restrict__ cls1,
        int* __restrict__ sel_idx) {
    int bid = blockIdx.x;            // 0..31
    int b = bid >> 1;
    int lvl = bid & 1;
    int n = (lvl == 0) ? 6400 : 1600;
    const float* cls = (lvl == 0 ? cls0 : cls1) + (size_t)b * n * NCLS;

    __shared__ unsigned int skey[6400];
    __shared__ unsigned int hist[256];
    __shared__ unsigned int s_prefix, s_kk, s_cnt;
    int t = threadIdx.x;

    for (int a = t; a < n; a += 256) {
        const float* p = cls + (size_t)a * NCLS;
        float m = p[0];
        #pragma unroll
        for (int c = 1; c < NCLS; ++c) m = fmaxf(m, p[c]);
        skey[a] = orderable(m);
    }
    if (t == 0) { s_kk = NPRE; s_prefix = 0u; s_cnt = 0u; }
    __syncthreads();

    // 4-pass radix select for the NPRE-th largest key
    for (int pass = 0; pass < 4; ++pass) {
        int shift = 24 - 8 * pass;
        for (int i = t; i < 256; i += 256) hist[i] = 0u;
        __syncthreads();
        unsigned int prefix = s_prefix;
        for (int a = t; a < n; a += 256) {
            unsigned int u = skey[a];
            if (pass == 0 || (u >> (shift + 8)) == prefix)
                atomicAdd(&hist[(u >> shift) & 255u], 1u);
        }
        __syncthreads();
        if (t == 0) {
            unsigned int kk = s_kk, cum = 0u; int digit = 0;
            for (int bin = 255; bin >= 0; --bin) {
                unsigned int h = hist[bin];
                if (cum + h >= kk) { digit = bin; s_kk = kk - cum; break; }
                cum += h;
            }
            s_prefix = (prefix << 8) | (unsigned int)digit;
        }
        __syncthreads();
    }

    unsigned int T = s_prefix;   // the NPRE-th largest key value
    int* out = sel_idx + b * 2000 + lvl * 1000;
    // all strictly-greater keys (count = NPRE - s_kk), order irrelevant
    for (int a = t; a < n; a += 256) {
        if (skey[a] > T) {
            unsigned int pos = atomicAdd(&s_cnt, 1u);
            out[pos] = a;
        }
    }
    __syncthreads();
    // fill remaining slots with ==T keys in ascending index order (top_k tie-break)
    if (t == 0) {
        unsigned int pos = s_cnt;
        unsigned int rem = s_kk;
        for (int a = 0; a < n && rem > 0u; ++a) {
            if (skey[a] == T) { out[pos++] = a; --rem; }
        }
    }
}

// ============================================================
// Kernel 2: decode scores (sigmoid) + DFL boxes for the 2400
// selected anchors per batch.
// ============================================================
__global__ __launch_bounds__(256) void decode_kernel(
        const float* __restrict__ cls0, const float* __restrict__ cls1, const float* __restrict__ cls2,
        const float* __restrict__ bb0,  const float* __restrict__ bb1,  const float* __restrict__ bb2,
        const int* __restrict__ sel_idx,
        float* __restrict__ boxes_all, float* __restrict__ scores_all) {
    int tg = blockIdx.x * blockDim.x + threadIdx.x;
    if (tg >= BATCH * NTOT) return;
    int b = tg / NTOT, j = tg % NTOT;

    const float* cls; const float* bb; int a, w; float stride;
    if (j < 1000) {
        a = sel_idx[b * 2000 + j]; w = 80; stride = 8.f;
        cls = cls0 + ((size_t)b * 6400 + a) * NCLS;
        bb  = bb0  + ((size_t)b * 6400 + a) * 32;
    } else if (j < 2000) {
        a = sel_idx[b * 2000 + j]; w = 40; stride = 16.f;
        cls = cls1 + ((size_t)b * 1600 + a) * NCLS;
        bb  = bb1  + ((size_t)b * 1600 + a) * 32;
    } else {
        a = j - 2000; w = 20; stride = 32.f;
        cls = cls2 + ((size_t)b * 400 + a) * NCLS;
        bb  = bb2  + ((size_t)b * 400 + a) * 32;
    }

    float* sc = scores_all + ((size_t)b * NTOT + j) * NCLS;
    #pragma unroll
    for (int c = 0; c < NCLS; ++c) sc[c] = 1.f / (1.f + expf(-cls[c]));

    float d[4];
    #pragma unroll
    for (int s = 0; s < 4; ++s) {
        const float* l = bb + s * NBINS;
        float m = l[0];
        #pragma unroll
        for (int k = 1; k < NBINS; ++k) m = fmaxf(m, l[k]);
        float e[NBINS], sum = 0.f;
        #pragma unroll
        for (int k = 0; k < NBINS; ++k) { e[k] = expf(l[k] - m); sum += e[k]; }
        float acc = 0.f;
        #pragma unroll
        for (int k = 0; k < NBINS; ++k) acc += (e[k] / sum) * (float)k;
        d[s] = acc * stride;
    }
    float cy = ((float)(a / w) + 0.5f) * stride;
    float cx = ((float)(a % w) + 0.5f) * stride;
    float* bx = boxes_all + ((size_t)b * NTOT + j) * 4;
    bx[0] = fminf(fmaxf(cy - d[0], 0.f), 640.f);   // y1
    bx[1] = fminf(fmaxf(cx - d[1], 0.f), 640.f);   // x1
    bx[2] = fminf(fmaxf(cy + d[2], 0.f), 640.f);   // y2
    bx[3] = fminf(fmaxf(cx + d[3], 0.f), 640.f);   // x2
}

// ============================================================
// Kernel 3: greedy NMS, one block per (batch, class).
// ============================================================
__global__ __launch_bounds__(256) void nms_kernel(
        const float* __restrict__ boxes_all, const float* __restrict__ scores_all,
        float* __restrict__ nms_score, int* __restrict__ nms_idx) {
    int b = blockIdx.x / NCLS, c = blockIdx.x % NCLS;
    __shared__ float4 sbox[NTOT];          // 38400 B
    __shared__ float  ss[NTOT];            //  9600 B
    __shared__ float  rv[256];
    __shared__ int    ri[256];
    int t = threadIdx.x;

    const float4* bsrc = (const float4*)boxes_all + (size_t)b * NTOT;
    for (int j = t; j < NTOT; j += 256) {
        sbox[j] = bsrc[j];
        ss[j] = scores_all[((size_t)b * NTOT + j) * NCLS + c];
    }
    __syncthreads();

    float* osc = nms_score + ((size_t)b * NCLS + c) * TOPK;
    int*   oid = nms_idx   + ((size_t)b * NCLS + c) * TOPK;

    for (int k = 0; k < TOPK; ++k) {
        // block argmax, tie -> lowest index (matches jnp.argmax; all -inf -> 0)
        float v = -INFINITY; int bi = NTOT;
        for (int j = t; j < NTOT; j += 256) {
            float s = ss[j];
            if (s > v || (s == v && j < bi)) { v = s; bi = j; }
        }
        rv[t] = v; ri[t] = bi;
        __syncthreads();
        for (int s2 = 128; s2 > 0; s2 >>= 1) {
            if (t < s2) {
                float ov = rv[t + s2]; int oi = ri[t + s2];
                if (ov > rv[t] || (ov == rv[t] && oi < ri[t])) { rv[t] = ov; ri[t] = oi; }
            }
            __syncthreads();
        }
        int i = ri[0]; float sc = rv[0];

        if (sc == -INFINITY) {
            // all remaining iterations deterministically record (-inf, 0)
            for (int k2 = k + t; k2 < TOPK; k2 += 256) { osc[k2] = -INFINITY; oid[k2] = 0; }
            break;
        }
        if (t == 0) { osc[k] = sc; oid[k] = i; }

        float4 bi4 = sbox[i];
        float a1 = (bi4.z - bi4.x) * (bi4.w - bi4.y);
        for (int j = t; j < NTOT; j += 256) {
            float4 bj = sbox[j];
            float yy1 = fmaxf(bi4.x, bj.x);
            float xx1 = fmaxf(bi4.y, bj.y);
            float yy2 = fminf(bi4.z, bj.z);
            float xx2 = fminf(bi4.w, bj.w);
            float inter = fmaxf(yy2 - yy1, 0.f) * fmaxf(xx2 - xx1, 0.f);
            float a2 = (bj.z - bj.x) * (bj.w - bj.y);
            float iou = inter / (a1 + a2 - inter + 1e-9f);
            if (iou > 0.5f || j == i) ss[j] = -INFINITY;
        }
        __syncthreads();
    }
}

// ============================================================
// Kernel 4: per-batch global top-100 over 20*100 selections,
// exact reference ordering (desc score, asc flat index on tie),
// apply ok/>0.3 masking, write [B,100,6] output.
// ============================================================
__global__ __launch_bounds__(256) void final_kernel(
        const float* __restrict__ nms_score, const int* __restrict__ nms_idx,
        const float* __restrict__ boxes_all, float* __restrict__ out) {
    int b = blockIdx.x;
    int t = threadIdx.x;
    __shared__ unsigned long long keys[2000];  // 16000 B
    __shared__ float fs[2000];                 //  8000 B
    __shared__ unsigned long long rk[256];

    for (int f = t; f < 2000; f += 256) {
        float s = nms_score[(size_t)b * 2000 + f];
        float v = isfinite(s) ? s : -1.0f;
        fs[f] = v;
        keys[f] = ((unsigned long long)orderable(v) << 32)
                | (unsigned long long)(0xFFFFFFFFu - (unsigned int)f);
    }
    __syncthreads();

    for (int it = 0; it < TOPK; ++it) {
        unsigned long long best = 0ull;
        for (int f = t; f < 2000; f += 256) {
            unsigned long long kf = keys[f];
            best = (kf > best) ? kf : best;
        }
        rk[t] = best;
        __syncthreads();
        for (int s2 = 128; s2 > 0; s2 >>= 1) {
            if (t < s2) { unsigned long long o = rk[t + s2]; if (o > rk[t]) rk[t] = o; }
            __syncthreads();
        }
        unsigned long long kbest = rk[0];
        int fi = (int)(0xFFFFFFFFu - (unsigned int)(kbest & 0xFFFFFFFFull));
        if (t == 0) {
            float v = fs[fi];
            float* o = out + ((size_t)b * TOPK + it) * 6;
            if (v > 0.3f) {
                int cc = fi / TOPK;
                int bidx = nms_idx[(size_t)b * 2000 + fi];
                const float* bx = boxes_all + ((size_t)b * NTOT + bidx) * 4;
                o[0] = bx[0]; o[1] = bx[1]; o[2] = bx[2]; o[3] = bx[3];
                o[4] = v; o[5] = (float)cc;
            } else {
                o[0] = 0.f; o[1] = 0.f; o[2] = 0.f; o[3] = 0.f; o[4] = 0.f; o[5] = 0.f;
            }
            keys[fi] = 0ull;  // remove
        }
        __syncthreads();
    }
}

extern "C" void kernel_launch(void* const* d_in, const int* in_sizes, int n_in,
                              void* d_out, int out_size, void* d_ws, size_t ws_size,
                              hipStream_t stream) {
    (void)out_size; (void)ws_size;
    const float* cls[3] = {nullptr, nullptr, nullptr};
    const float* bbx[3] = {nullptr, nullptr, nullptr};
    for (int i = 0; i < n_in; ++i) {
        const float* p = (const float*)d_in[i];
        switch (in_sizes[i]) {
            case 16 * 6400 * 20: cls[0] = p; break;
            case 16 * 6400 * 32: bbx[0] = p; break;
            case 16 * 1600 * 20: cls[1] = p; break;
            case 16 * 1600 * 32: bbx[1] = p; break;
            case 16 *  400 * 20: cls[2] = p; break;
            case 16 *  400 * 32: bbx[2] = p; break;
            default: break;  // origin_shapes (unused by reference)
        }
    }

    char* w = (char*)d_ws;
    int*   sel_idx    = (int*)(w);                       // 16*2000*4   = 128000 B
    float* boxes_all  = (float*)(w + 131072);            // 16*2400*4*4 = 614400 B
    float* scores_all = (float*)(w + 131072 + 614400);   // 16*2400*20*4 = 3072000 B
    float* nms_score  = (float*)(w + 3817472);           // 16*20*100*4 = 128000 B
    int*   nms_idx    = (int*)(w + 3945472);             // 128000 B -> total ~3.9 MB

    hipLaunchKernelGGL(select_topk_kernel, dim3(32), dim3(256), 0, stream,
                       cls[0], cls[1], sel_idx);
    hipLaunchKernelGGL(decode_kernel, dim3((BATCH * NTOT + 255) / 256), dim3(256), 0, stream,
                       cls[0], cls[1], cls[2], bbx[0], bbx[1], bbx[2],
                       sel_idx, boxes_all, scores_all);
    hipLaunchKernelGGL(nms_kernel, dim3(BATCH * NCLS), dim3(256), 0, stream,
                       boxes_all, scores_all, nms_score, nms_idx);
    hipLaunchKernelGGL(final_kernel, dim3(BATCH), dim3(256), 0, stream,
                       nms_score, nms_idx, boxes_all, (float*)d_out);
}

// Round 2
// 549.605 us; speedup vs baseline: 1.8297x; 1.8297x over previous
//
#include <hip/hip_runtime.h>
#include <math.h>

#define BATCH 16
#define NCLS 20
#define TOPK 100
#define NPRE 1000
#define NTOT 2400
#define NBINS 8
#define N0 6400
#define N1 1600

// ---- order-preserving float->uint map (ascending) ----
__device__ __forceinline__ unsigned int orderable(float x) {
    unsigned int u = __float_as_uint(x);
    return (u & 0x80000000u) ? ~u : (u | 0x80000000u);
}

// ============================================================
// Kernel 0: massively-parallel per-anchor key = orderable(max_c logit).
// One thread per anchor; rows are 80 B (16B-aligned) -> float4 x5.
// ============================================================
__global__ __launch_bounds__(256) void compute_keys_kernel(
        const float* __restrict__ cls0, const float* __restrict__ cls1,
        unsigned int* __restrict__ keys0, unsigned int* __restrict__ keys1) {
    int tg = blockIdx.x * 256 + threadIdx.x;
    const float* p;
    unsigned int* dst;
    if (tg < BATCH * N0) {
        p = cls0 + (size_t)tg * NCLS;
        dst = keys0 + tg;
    } else {
        int a = tg - BATCH * N0;
        if (a >= BATCH * N1) return;
        p = cls1 + (size_t)a * NCLS;
        dst = keys1 + a;
    }
    const float4* p4 = (const float4*)p;
    float m = -INFINITY;
    #pragma unroll
    for (int q = 0; q < 5; ++q) {
        float4 v = p4[q];
        m = fmaxf(m, fmaxf(fmaxf(v.x, v.y), fmaxf(v.z, v.w)));
    }
    *dst = orderable(m);
}

// ============================================================
// Kernel 1: per (batch, level in {0,1}) exact top-1000 radix select
// over precomputed 4-byte keys.
// ============================================================
__global__ __launch_bounds__(256) void radix_select_kernel(
        const unsigned int* __restrict__ keys0, const unsigned int* __restrict__ keys1,
        int* __restrict__ sel_idx) {
    int bid = blockIdx.x;            // 0..31
    int b = bid >> 1;
    int lvl = bid & 1;
    int n = (lvl == 0) ? N0 : N1;
    const unsigned int* gk = (lvl == 0 ? keys0 : keys1) + (size_t)b * n;

    __shared__ unsigned int skey[N0];
    __shared__ unsigned int hist[256];
    __shared__ int eq[256];
    __shared__ unsigned int s_prefix, s_kk, s_cnt, s_eqcnt;
    int t = threadIdx.x;

    for (int a = t; a < n; a += 256) skey[a] = gk[a];
    if (t == 0) { s_kk = NPRE; s_prefix = 0u; s_cnt = 0u; s_eqcnt = 0u; }
    __syncthreads();

    // 4-pass radix select for the NPRE-th largest key
    for (int pass = 0; pass < 4; ++pass) {
        int shift = 24 - 8 * pass;
        hist[t] = 0u;
        __syncthreads();
        unsigned int prefix = s_prefix;
        for (int a = t; a < n; a += 256) {
            unsigned int u = skey[a];
            if (pass == 0 || (u >> (shift + 8)) == prefix)
                atomicAdd(&hist[(u >> shift) & 255u], 1u);
        }
        __syncthreads();
        if (t == 0) {
            unsigned int kk = s_kk, cum = 0u; int digit = 0;
            for (int bin = 255; bin >= 0; --bin) {
                unsigned int h = hist[bin];
                if (cum + h >= kk) { digit = bin; s_kk = kk - cum; break; }
                cum += h;
            }
            s_prefix = (prefix << 8) | (unsigned int)digit;
        }
        __syncthreads();
    }

    unsigned int T = s_prefix;   // the NPRE-th largest key value
    int* out = sel_idx + b * 2000 + lvl * 1000;
    // strictly-greater keys (count = NPRE - s_kk), order irrelevant for NMS;
    // also collect ==T indices in parallel
    for (int a = t; a < n; a += 256) {
        unsigned int u = skey[a];
        if (u > T) {
            unsigned int pos = atomicAdd(&s_cnt, 1u);
            out[pos] = a;
        } else if (u == T) {
            unsigned int p = atomicAdd(&s_eqcnt, 1u);
            if (p < 256u) eq[p] = a;
        }
    }
    __syncthreads();
    // fill remaining slots with ==T keys in ascending index order (top_k tie-break)
    if (t == 0) {
        unsigned int pos = s_cnt;
        unsigned int rem = s_kk;
        unsigned int cnt = s_eqcnt;
        if (cnt <= 256u) {
            // insertion-sort the (tiny, typically 1-element) equal list
            for (unsigned int i = 1; i < cnt; ++i) {
                int key = eq[i]; int j2 = (int)i - 1;
                while (j2 >= 0 && eq[j2] > key) { eq[j2 + 1] = eq[j2]; --j2; }
                eq[j2 + 1] = key;
            }
            for (unsigned int i = 0; i < rem; ++i) out[pos + i] = eq[i];
        } else {
            for (int a = 0; a < n && rem > 0u; ++a)
                if (skey[a] == T) { out[pos++] = a; --rem; }
        }
    }
}

// ============================================================
// Kernel 2: decode scores (sigmoid, TRANSPOSED [b][c][j]) + DFL boxes
// for the 2400 selected anchors per batch.
// ============================================================
__global__ __launch_bounds__(256) void decode_kernel(
        const float* __restrict__ cls0, const float* __restrict__ cls1, const float* __restrict__ cls2,
        const float* __restrict__ bb0,  const float* __restrict__ bb1,  const float* __restrict__ bb2,
        const int* __restrict__ sel_idx,
        float* __restrict__ boxes_all, float* __restrict__ scores_t) {
    int tg = blockIdx.x * blockDim.x + threadIdx.x;
    if (tg >= BATCH * NTOT) return;
    int b = tg / NTOT, j = tg % NTOT;

    const float* cls; const float* bb; int a, w; float stride;
    if (j < 1000) {
        a = sel_idx[b * 2000 + j]; w = 80; stride = 8.f;
        cls = cls0 + ((size_t)b * N0 + a) * NCLS;
        bb  = bb0  + ((size_t)b * N0 + a) * 32;
    } else if (j < 2000) {
        a = sel_idx[b * 2000 + j]; w = 40; stride = 16.f;
        cls = cls1 + ((size_t)b * N1 + a) * NCLS;
        bb  = bb1  + ((size_t)b * N1 + a) * 32;
    } else {
        a = j - 2000; w = 20; stride = 32.f;
        cls = cls2 + ((size_t)b * 400 + a) * NCLS;
        bb  = bb2  + ((size_t)b * 400 + a) * 32;
    }

    // transposed score write: consecutive threads (same b,c) -> consecutive j
    #pragma unroll
    for (int c = 0; c < NCLS; ++c)
        scores_t[((size_t)b * NCLS + c) * NTOT + j] = 1.f / (1.f + expf(-cls[c]));

    float d[4];
    #pragma unroll
    for (int s = 0; s < 4; ++s) {
        const float* l = bb + s * NBINS;
        float m = l[0];
        #pragma unroll
        for (int k = 1; k < NBINS; ++k) m = fmaxf(m, l[k]);
        float e[NBINS], sum = 0.f;
        #pragma unroll
        for (int k = 0; k < NBINS; ++k) { e[k] = expf(l[k] - m); sum += e[k]; }
        float acc = 0.f;
        #pragma unroll
        for (int k = 0; k < NBINS; ++k) acc += (e[k] / sum) * (float)k;
        d[s] = acc * stride;
    }
    float cy = ((float)(a / w) + 0.5f) * stride;
    float cx = ((float)(a % w) + 0.5f) * stride;
    float* bx = boxes_all + ((size_t)b * NTOT + j) * 4;
    bx[0] = fminf(fmaxf(cy - d[0], 0.f), 640.f);   // y1
    bx[1] = fminf(fmaxf(cx - d[1], 0.f), 640.f);   // x1
    bx[2] = fminf(fmaxf(cy + d[2], 0.f), 640.f);   // y2
    bx[3] = fminf(fmaxf(cx + d[3], 0.f), 640.f);   // x2
}

// ---- block argmax helper pieces (value, index), tie -> lowest index ----
__device__ __forceinline__ void argmax_reduce_block(
        float v, int bi, float* s_bv, int* s_bi,
        float* pv, int* pi, int t) {
    // wave-level shuffle reduce (64 lanes)
    #pragma unroll
    for (int off = 32; off > 0; off >>= 1) {
        float ov = __shfl_down(v, off);
        int   oi = __shfl_down(bi, off);
        if (ov > v || (ov == v && oi < bi)) { v = ov; bi = oi; }
    }
    int wave = t >> 6;
    if ((t & 63) == 0) { pv[wave] = v; pi[wave] = bi; }
    __syncthreads();
    if (t == 0) {
        float bv = pv[0]; int bb2 = pi[0];
        #pragma unroll
        for (int w = 1; w < 4; ++w) {
            float ov = pv[w]; int oi = pi[w];
            if (ov > bv || (ov == bv && oi < bb2)) { bv = ov; bb2 = oi; }
        }
        *s_bv = bv; *s_bi = bb2;
    }
    __syncthreads();
}

// ============================================================
// Kernel 3: greedy NMS, one block per (batch, class).
// Fused suppression + next-argmax single LDS pass per iteration.
// ============================================================
__global__ __launch_bounds__(256) void nms_kernel(
        const float* __restrict__ boxes_all, const float* __restrict__ scores_t,
        float* __restrict__ nms_score, int* __restrict__ nms_idx) {
    int b = blockIdx.x / NCLS, c = blockIdx.x % NCLS;
    __shared__ float4 sbox[NTOT];          // 38400 B
    __shared__ float  ss[NTOT];            //  9600 B
    __shared__ float  pv[4];
    __shared__ int    pi[4];
    __shared__ float  s_bv;
    __shared__ int    s_bi;
    int t = threadIdx.x;

    const float4* bsrc = (const float4*)boxes_all + (size_t)b * NTOT;
    const float* ssrc = scores_t + ((size_t)b * NCLS + c) * NTOT;
    for (int j = t; j < NTOT; j += 256) {
        sbox[j] = bsrc[j];
        ss[j] = ssrc[j];
    }
    __syncthreads();

    float* osc = nms_score + ((size_t)b * NCLS + c) * TOPK;
    int*   oid = nms_idx   + ((size_t)b * NCLS + c) * TOPK;

    // initial argmax
    {
        float v = -INFINITY; int bi = NTOT;
        for (int j = t; j < NTOT; j += 256) {
            float s = ss[j];
            if (s > v) { v = s; bi = j; }
        }
        argmax_reduce_block(v, bi, &s_bv, &s_bi, pv, pi, t);
    }

    for (int k = 0; k < TOPK; ++k) {
        int i = s_bi; float sc = s_bv;
        if (sc == -INFINITY) {
            for (int k2 = k + t; k2 < TOPK; k2 += 256) { osc[k2] = -INFINITY; oid[k2] = 0; }
            break;
        }
        if (t == 0) { osc[k] = sc; oid[k] = i; }
        if (k == TOPK - 1) break;

        // fused: suppress vs winner i, track next argmax in the same pass
        float4 bi4 = sbox[i];
        float a1 = (bi4.z - bi4.x) * (bi4.w - bi4.y);
        float v = -INFINITY; int bi = NTOT;
        for (int j = t; j < NTOT; j += 256) {
            float s = ss[j];
            if (s != -INFINITY) {
                float4 bj = sbox[j];
                float yy1 = fmaxf(bi4.x, bj.x);
                float xx1 = fmaxf(bi4.y, bj.y);
                float yy2 = fminf(bi4.z, bj.z);
                float xx2 = fminf(bi4.w, bj.w);
                float inter = fmaxf(yy2 - yy1, 0.f) * fmaxf(xx2 - xx1, 0.f);
                float a2 = (bj.z - bj.x) * (bj.w - bj.y);
                float iou = inter / (a1 + a2 - inter + 1e-9f);
                if (iou > 0.5f || j == i) { s = -INFINITY; ss[j] = -INFINITY; }
            }
            if (s > v) { v = s; bi = j; }
        }
        argmax_reduce_block(v, bi, &s_bv, &s_bi, pv, pi, t);
    }
}

// ============================================================
// Kernel 4: per-batch global top-100 over 20*100 selections,
// exact reference ordering (desc score, asc flat index on tie),
// fused remove + next-argmax per iteration.
// ============================================================
__global__ __launch_bounds__(256) void final_kernel(
        const float* __restrict__ nms_score, const int* __restrict__ nms_idx,
        const float* __restrict__ boxes_all, float* __restrict__ out) {
    int b = blockIdx.x;
    int t = threadIdx.x;
    __shared__ unsigned long long keys[2000];  // 16000 B
    __shared__ float fs[2000];                 //  8000 B
    __shared__ unsigned long long pk[4];
    __shared__ unsigned long long s_k;

    for (int f = t; f < 2000; f += 256) {
        float s = nms_score[(size_t)b * 2000 + f];
        float v = isfinite(s) ? s : -1.0f;
        fs[f] = v;
        keys[f] = ((unsigned long long)orderable(v) << 32)
                | (unsigned long long)(0xFFFFFFFFu - (unsigned int)f);
    }
    __syncthreads();

    for (int it = 0; it < TOPK; ++it) {
        // scan for max key
        unsigned long long best = 0ull;
        for (int f = t; f < 2000; f += 256) {
            unsigned long long kf = keys[f];
            best = (kf > best) ? kf : best;
        }
        #pragma unroll
        for (int off = 32; off > 0; off >>= 1) {
            unsigned long long o = __shfl_down(best, off);
            best = (o > best) ? o : best;
        }
        int wave = t >> 6;
        if ((t & 63) == 0) pk[wave] = best;
        __syncthreads();
        if (t == 0) {
            unsigned long long bv = pk[0];
            #pragma unroll
            for (int w = 1; w < 4; ++w) bv = (pk[w] > bv) ? pk[w] : bv;
            s_k = bv;
        }
        __syncthreads();
        unsigned long long kbest = s_k;
        int fi = (int)(0xFFFFFFFFu - (unsigned int)(kbest & 0xFFFFFFFFull));
        if (t == 0) {
            float v = fs[fi];
            float* o = out + ((size_t)b * TOPK + it) * 6;
            if (v > 0.3f) {
                int cc = fi / TOPK;
                int bidx = nms_idx[(size_t)b * 2000 + fi];
                const float* bx = boxes_all + ((size_t)b * NTOT + bidx) * 4;
                o[0] = bx[0]; o[1] = bx[1]; o[2] = bx[2]; o[3] = bx[3];
                o[4] = v; o[5] = (float)cc;
            } else {
                o[0] = 0.f; o[1] = 0.f; o[2] = 0.f; o[3] = 0.f; o[4] = 0.f; o[5] = 0.f;
            }
            keys[fi] = 0ull;  // remove
        }
        __syncthreads();
    }
}

extern "C" void kernel_launch(void* const* d_in, const int* in_sizes, int n_in,
                              void* d_out, int out_size, void* d_ws, size_t ws_size,
                              hipStream_t stream) {
    (void)out_size; (void)ws_size;
    const float* cls[3] = {nullptr, nullptr, nullptr};
    const float* bbx[3] = {nullptr, nullptr, nullptr};
    for (int i = 0; i < n_in; ++i) {
        const float* p = (const float*)d_in[i];
        switch (in_sizes[i]) {
            case 16 * 6400 * 20: cls[0] = p; break;
            case 16 * 6400 * 32: bbx[0] = p; break;
            case 16 * 1600 * 20: cls[1] = p; break;
            case 16 * 1600 * 32: bbx[1] = p; break;
            case 16 *  400 * 20: cls[2] = p; break;
            case 16 *  400 * 32: bbx[2] = p; break;
            default: break;  // origin_shapes (unused by reference)
        }
    }

    // workspace layout (keys aliased onto scores_t: keys die before decode writes it)
    char* w = (char*)d_ws;
    int*   sel_idx    = (int*)(w);                       // 128000 B (round to 131072)
    float* boxes_all  = (float*)(w + 131072);            // 16*2400*16 = 614400 B
    float* scores_t   = (float*)(w + 745472);            // 16*20*2400*4 = 3072000 B
    unsigned int* keys0 = (unsigned int*)(w + 745472);           // 409600 B (aliased)
    unsigned int* keys1 = (unsigned int*)(w + 745472 + 409600);  // 102400 B (aliased)
    float* nms_score  = (float*)(w + 3817472);           // 128000 B
    int*   nms_idx    = (int*)(w + 3945472);             // 128000 B -> total 4073472 B

    hipLaunchKernelGGL(compute_keys_kernel, dim3((BATCH * (N0 + N1) + 255) / 256), dim3(256), 0, stream,
                       cls[0], cls[1], keys0, keys1);
    hipLaunchKernelGGL(radix_select_kernel, dim3(32), dim3(256), 0, stream,
                       keys0, keys1, sel_idx);
    hipLaunchKernelGGL(decode_kernel, dim3((BATCH * NTOT + 255) / 256), dim3(256), 0, stream,
                       cls[0], cls[1], cls[2], bbx[0], bbx[1], bbx[2],
                       sel_idx, boxes_all, scores_t);
    hipLaunchKernelGGL(nms_kernel, dim3(BATCH * NCLS), dim3(256), 0, stream,
                       boxes_all, scores_t, nms_score, nms_idx);
    hipLaunchKernelGGL(final_kernel, dim3(BATCH), dim3(256), 0, stream,
                       nms_score, nms_idx, boxes_all, (float*)d_out);
}

// Round 3
// 333.699 us; speedup vs baseline: 3.0136x; 1.6470x over previous
//
#include <hip/hip_runtime.h>
#include <math.h>

#define BATCH 16
#define NCLS 20
#define TOPK 100
#define NPRE 1000
#define NTOT 2400
#define NBINS 8
#define N0 6400
#define N1 1600

// ---- order-preserving float->uint map (ascending) ----
__device__ __forceinline__ unsigned int orderable(float x) {
    unsigned int u = __float_as_uint(x);
    return (u & 0x80000000u) ? ~u : (u | 0x80000000u);
}
__device__ __forceinline__ float unorderable(unsigned int k) {
    return __uint_as_float((k & 0x80000000u) ? (k ^ 0x80000000u) : ~k);
}

// ============================================================
// Kernel 0: per-anchor key = orderable(max_c logit).
// ============================================================
__global__ __launch_bounds__(256) void compute_keys_kernel(
        const float* __restrict__ cls0, const float* __restrict__ cls1,
        unsigned int* __restrict__ keys0, unsigned int* __restrict__ keys1) {
    int tg = blockIdx.x * 256 + threadIdx.x;
    const float* p;
    unsigned int* dst;
    if (tg < BATCH * N0) {
        p = cls0 + (size_t)tg * NCLS;
        dst = keys0 + tg;
    } else {
        int a = tg - BATCH * N0;
        if (a >= BATCH * N1) return;
        p = cls1 + (size_t)a * NCLS;
        dst = keys1 + a;
    }
    const float4* p4 = (const float4*)p;
    float m = -INFINITY;
    #pragma unroll
    for (int q = 0; q < 5; ++q) {
        float4 v = p4[q];
        m = fmaxf(m, fmaxf(fmaxf(v.x, v.y), fmaxf(v.z, v.w)));
    }
    *dst = orderable(m);
}

// ============================================================
// Kernel 1: per (batch, level) exact top-1000 radix select.
// Parallel suffix-scan replaces the serial 256-bin walk.
// ============================================================
__global__ __launch_bounds__(256) void radix_select_kernel(
        const unsigned int* __restrict__ keys0, const unsigned int* __restrict__ keys1,
        int* __restrict__ sel_idx) {
    int bid = blockIdx.x;            // 0..31
    int b = bid >> 1;
    int lvl = bid & 1;
    int n = (lvl == 0) ? N0 : N1;
    const unsigned int* gk = (lvl == 0 ? keys0 : keys1) + (size_t)b * n;

    __shared__ unsigned int skey[N0];
    __shared__ unsigned int hist[256];
    __shared__ unsigned int sfxA[257], sfxB[257];
    __shared__ int eq[256];
    __shared__ unsigned int s_prefix, s_kk, s_cnt, s_eqcnt;
    int t = threadIdx.x;

    for (int a = t; a < n; a += 256) skey[a] = gk[a];
    if (t == 0) {
        s_kk = NPRE; s_prefix = 0u; s_cnt = 0u; s_eqcnt = 0u;
        sfxA[256] = 0u; sfxB[256] = 0u;
    }
    __syncthreads();

    for (int pass = 0; pass < 4; ++pass) {
        int shift = 24 - 8 * pass;
        hist[t] = 0u;
        __syncthreads();
        unsigned int prefix = s_prefix, kk = s_kk;
        for (int a = t; a < n; a += 256) {
            unsigned int u = skey[a];
            if (pass == 0 || (u >> (shift + 8)) == prefix)
                atomicAdd(&hist[(u >> shift) & 255u], 1u);
        }
        __syncthreads();
        sfxA[t] = hist[t];
        __syncthreads();
        // inclusive suffix sum, Hillis-Steele, ping-pong
        unsigned int* src = sfxA; unsigned int* dst = sfxB;
        #pragma unroll
        for (int step = 1; step < 256; step <<= 1) {
            int idx = t + step; if (idx > 256) idx = 256;
            dst[t] = src[t] + src[idx];
            __syncthreads();
            unsigned int* tmp = src; src = dst; dst = tmp;
        }
        unsigned int Sd = src[t];
        unsigned int Sd1 = src[t + 1];
        if (Sd >= kk && Sd1 < kk) {
            s_prefix = (prefix << 8) | (unsigned int)t;
            s_kk = kk - Sd1;
        }
        __syncthreads();
    }

    unsigned int T = s_prefix;   // the NPRE-th largest key value
    int* out = sel_idx + b * 2000 + lvl * 1000;
    for (int a = t; a < n; a += 256) {
        unsigned int u = skey[a];
        if (u > T) {
            unsigned int pos = atomicAdd(&s_cnt, 1u);
            out[pos] = a;
        } else if (u == T) {
            unsigned int p = atomicAdd(&s_eqcnt, 1u);
            if (p < 256u) eq[p] = a;
        }
    }
    __syncthreads();
    if (t == 0) {
        unsigned int pos = s_cnt;
        unsigned int rem = s_kk;
        unsigned int cnt = s_eqcnt;
        if (cnt <= 256u) {
            for (unsigned int i = 1; i < cnt; ++i) {
                int key = eq[i]; int j2 = (int)i - 1;
                while (j2 >= 0 && eq[j2] > key) { eq[j2 + 1] = eq[j2]; --j2; }
                eq[j2 + 1] = key;
            }
            for (unsigned int i = 0; i < rem; ++i) out[pos + i] = eq[i];
        } else {
            for (int a = 0; a < n && rem > 0u; ++a)
                if (skey[a] == T) { out[pos++] = a; --rem; }
        }
    }
}

// ============================================================
// Kernel 2: decode scores (sigmoid, transposed [b][c][j]) + DFL boxes.
// ============================================================
__global__ __launch_bounds__(256) void decode_kernel(
        const float* __restrict__ cls0, const float* __restrict__ cls1, const float* __restrict__ cls2,
        const float* __restrict__ bb0,  const float* __restrict__ bb1,  const float* __restrict__ bb2,
        const int* __restrict__ sel_idx,
        float* __restrict__ boxes_all, float* __restrict__ scores_t) {
    int tg = blockIdx.x * blockDim.x + threadIdx.x;
    if (tg >= BATCH * NTOT) return;
    int b = tg / NTOT, j = tg % NTOT;

    const float* cls; const float* bb; int a, w; float stride;
    if (j < 1000) {
        a = sel_idx[b * 2000 + j]; w = 80; stride = 8.f;
        cls = cls0 + ((size_t)b * N0 + a) * NCLS;
        bb  = bb0  + ((size_t)b * N0 + a) * 32;
    } else if (j < 2000) {
        a = sel_idx[b * 2000 + j]; w = 40; stride = 16.f;
        cls = cls1 + ((size_t)b * N1 + a) * NCLS;
        bb  = bb1  + ((size_t)b * N1 + a) * 32;
    } else {
        a = j - 2000; w = 20; stride = 32.f;
        cls = cls2 + ((size_t)b * 400 + a) * NCLS;
        bb  = bb2  + ((size_t)b * 400 + a) * 32;
    }

    // vectorized row loads
    float cl[20];
    {
        const float4* c4 = (const float4*)cls;
        #pragma unroll
        for (int q = 0; q < 5; ++q) *(float4*)&cl[q * 4] = c4[q];
    }
    float bl[32];
    {
        const float4* b4 = (const float4*)bb;
        #pragma unroll
        for (int q = 0; q < 8; ++q) *(float4*)&bl[q * 4] = b4[q];
    }

    #pragma unroll
    for (int c = 0; c < NCLS; ++c)
        scores_t[((size_t)b * NCLS + c) * NTOT + j] = 1.f / (1.f + expf(-cl[c]));

    float d[4];
    #pragma unroll
    for (int s = 0; s < 4; ++s) {
        const float* l = &bl[s * NBINS];
        float m = l[0];
        #pragma unroll
        for (int k = 1; k < NBINS; ++k) m = fmaxf(m, l[k]);
        float e[NBINS], sum = 0.f;
        #pragma unroll
        for (int k = 0; k < NBINS; ++k) { e[k] = expf(l[k] - m); sum += e[k]; }
        float acc = 0.f;
        #pragma unroll
        for (int k = 0; k < NBINS; ++k) acc += (e[k] / sum) * (float)k;
        d[s] = acc * stride;
    }
    float cy = ((float)(a / w) + 0.5f) * stride;
    float cx = ((float)(a % w) + 0.5f) * stride;
    float* bx = boxes_all + ((size_t)b * NTOT + j) * 4;
    bx[0] = fminf(fmaxf(cy - d[0], 0.f), 640.f);   // y1
    bx[1] = fminf(fmaxf(cx - d[1], 0.f), 640.f);   // x1
    bx[2] = fminf(fmaxf(cy + d[2], 0.f), 640.f);   // y2
    bx[3] = fminf(fmaxf(cx + d[3], 0.f), 640.f);   // x2
}

// ---- block argmax: result returned to ALL lanes; one barrier; caller
// alternates `buf` (parity double-buffer) to avoid WAR barriers ----
__device__ __forceinline__ void block_argmax(
        float v, int bi, float* pv, int* pi, int t, int buf,
        float& wv, int& wi) {
    #pragma unroll
    for (int off = 32; off > 0; off >>= 1) {
        float ov = __shfl_down(v, off);
        int   oi = __shfl_down(bi, off);
        if (ov > v || (ov == v && oi < bi)) { v = ov; bi = oi; }
    }
    if ((t & 63) == 0) { pv[buf * 4 + (t >> 6)] = v; pi[buf * 4 + (t >> 6)] = bi; }
    __syncthreads();
    wv = pv[buf * 4]; wi = pi[buf * 4];
    #pragma unroll
    for (int w = 1; w < 4; ++w) {
        float ov = pv[buf * 4 + w]; int oi = pi[buf * 4 + w];
        if (ov > wv || (ov == wv && oi < wi)) { wv = ov; wi = oi; }
    }
}

// ============================================================
// Kernel 3: greedy NMS, one block per (batch, class).
// Scores + boxes in REGISTERS (10 slots/thread, branchless);
// LDS only for winner-box broadcast. One barrier per iteration.
// ============================================================
__global__ __launch_bounds__(256) void nms_kernel(
        const float* __restrict__ boxes_all, const float* __restrict__ scores_t,
        float* __restrict__ nms_score, int* __restrict__ nms_idx) {
    int b = blockIdx.x / NCLS, c = blockIdx.x % NCLS;
    __shared__ float4 sbox[NTOT];          // 38400 B (winner broadcast)
    __shared__ float  pv[8];
    __shared__ int    pi[8];
    int t = threadIdx.x;

    const float4* bsrc = (const float4*)boxes_all + (size_t)b * NTOT;
    const float*  ssrc = scores_t + ((size_t)b * NCLS + c) * NTOT;

    float  sc[10];
    float4 bx[10];
    #pragma unroll
    for (int s = 0; s < 10; ++s) {
        int j = t + s * 256;
        if (j < NTOT) {
            float4 bj = bsrc[j];
            sbox[j] = bj;
            bx[s] = bj;
            sc[s] = ssrc[j];
        } else {
            bx[s] = make_float4(0.f, 0.f, 0.f, 0.f);
            sc[s] = -INFINITY;
        }
    }
    __syncthreads();

    float* osc = nms_score + ((size_t)b * NCLS + c) * TOPK;
    int*   oid = nms_idx   + ((size_t)b * NCLS + c) * TOPK;

    // initial argmax
    float v = -INFINITY; int bi = 0x7FFFFFFF;
    #pragma unroll
    for (int s = 0; s < 10; ++s) {
        int j = t + s * 256;
        if (sc[s] > v) { v = sc[s]; bi = j; }
    }
    float wv; int wi;
    block_argmax(v, bi, pv, pi, t, 0, wv, wi);
    int buf = 1;

    for (int k = 0; k < TOPK; ++k) {
        if (wv == -INFINITY) {
            for (int k2 = k + t; k2 < TOPK; k2 += 256) { osc[k2] = -INFINITY; oid[k2] = 0; }
            break;
        }
        if (t == 0) { osc[k] = wv; oid[k] = wi; }
        if (k == TOPK - 1) break;

        float4 wb = sbox[wi];   // LDS broadcast (same address all lanes)
        float a1 = (wb.z - wb.x) * (wb.w - wb.y);
        float v2 = -INFINITY; int bi2 = 0x7FFFFFFF;
        #pragma unroll
        for (int s = 0; s < 10; ++s) {
            int j = t + s * 256;
            float4 bj = bx[s];
            float yy1 = fmaxf(wb.x, bj.x);
            float xx1 = fmaxf(wb.y, bj.y);
            float yy2 = fminf(wb.z, bj.z);
            float xx2 = fminf(wb.w, bj.w);
            float inter = fmaxf(yy2 - yy1, 0.f) * fmaxf(xx2 - xx1, 0.f);
            float a2 = (bj.z - bj.x) * (bj.w - bj.y);
            float iou = inter / (a1 + a2 - inter + 1e-9f);
            if (iou > 0.5f || j == wi) sc[s] = -INFINITY;
            if (sc[s] > v2) { v2 = sc[s]; bi2 = j; }
        }
        block_argmax(v2, bi2, pv, pi, t, buf, wv, wi);
        buf ^= 1;
    }
}

// ============================================================
// Kernel 4: per-batch global top-100. u64 keys in registers
// (8 slots/thread); selected boxes pre-gathered to LDS so the
// output path never touches global loads.
// ============================================================
__global__ __launch_bounds__(256) void final_kernel(
        const float* __restrict__ nms_score, const int* __restrict__ nms_idx,
        const float* __restrict__ boxes_all, float* __restrict__ out) {
    int b = blockIdx.x;
    int t = threadIdx.x;
    __shared__ float4 sb2[2000];               // 32000 B
    __shared__ unsigned long long pk[8];       // parity double-buffer

    unsigned long long key[8];
    #pragma unroll
    for (int s = 0; s < 8; ++s) {
        int f = t + s * 256;
        if (f < 2000) {
            float sc = nms_score[(size_t)b * 2000 + f];
            float v = isfinite(sc) ? sc : -1.0f;
            key[s] = ((unsigned long long)orderable(v) << 32)
                   | (unsigned long long)(0xFFFFFFFFu - (unsigned int)f);
        } else {
            key[s] = 0ull;
        }
    }
    const float4* boxes4 = (const float4*)boxes_all + (size_t)b * NTOT;
    for (int f = t; f < 2000; f += 256)
        sb2[f] = boxes4[nms_idx[(size_t)b * 2000 + f]];
    __syncthreads();

    int buf = 0;
    for (int it = 0; it < TOPK; ++it) {
        unsigned long long best = 0ull;
        #pragma unroll
        for (int s = 0; s < 8; ++s) best = (key[s] > best) ? key[s] : best;
        #pragma unroll
        for (int off = 32; off > 0; off >>= 1) {
            unsigned long long o = __shfl_down(best, off);
            best = (o > best) ? o : best;
        }
        if ((t & 63) == 0) pk[buf * 4 + (t >> 6)] = best;
        __syncthreads();
        unsigned long long kb = pk[buf * 4];
        #pragma unroll
        for (int w = 1; w < 4; ++w) kb = (pk[buf * 4 + w] > kb) ? pk[buf * 4 + w] : kb;
        buf ^= 1;

        int fi = (int)(0xFFFFFFFFu - (unsigned int)(kb & 0xFFFFFFFFull));
        float vwin = unorderable((unsigned int)(kb >> 32));
        if (t == 0) {
            float* o = out + ((size_t)b * TOPK + it) * 6;
            if (vwin > 0.3f) {
                float4 bxw = sb2[fi];
                o[0] = bxw.x; o[1] = bxw.y; o[2] = bxw.z; o[3] = bxw.w;
                o[4] = vwin; o[5] = (float)(fi / TOPK);
            } else {
                o[0] = 0.f; o[1] = 0.f; o[2] = 0.f; o[3] = 0.f; o[4] = 0.f; o[5] = 0.f;
            }
        }
        // branchless removal by owner slot
        #pragma unroll
        for (int s = 0; s < 8; ++s)
            if (t + s * 256 == fi) key[s] = 0ull;
    }
}

extern "C" void kernel_launch(void* const* d_in, const int* in_sizes, int n_in,
                              void* d_out, int out_size, void* d_ws, size_t ws_size,
                              hipStream_t stream) {
    (void)out_size; (void)ws_size;
    const float* cls[3] = {nullptr, nullptr, nullptr};
    const float* bbx[3] = {nullptr, nullptr, nullptr};
    for (int i = 0; i < n_in; ++i) {
        const float* p = (const float*)d_in[i];
        switch (in_sizes[i]) {
            case 16 * 6400 * 20: cls[0] = p; break;
            case 16 * 6400 * 32: bbx[0] = p; break;
            case 16 * 1600 * 20: cls[1] = p; break;
            case 16 * 1600 * 32: bbx[1] = p; break;
            case 16 *  400 * 20: cls[2] = p; break;
            case 16 *  400 * 32: bbx[2] = p; break;
            default: break;  // origin_shapes (unused by reference)
        }
    }

    // workspace layout (keys aliased onto scores_t: keys die before decode writes it)
    char* w = (char*)d_ws;
    int*   sel_idx    = (int*)(w);                       // 128000 B (round to 131072)
    float* boxes_all  = (float*)(w + 131072);            // 16*2400*16 = 614400 B
    float* scores_t   = (float*)(w + 745472);            // 16*20*2400*4 = 3072000 B
    unsigned int* keys0 = (unsigned int*)(w + 745472);           // 409600 B (aliased)
    unsigned int* keys1 = (unsigned int*)(w + 745472 + 409600);  // 102400 B (aliased)
    float* nms_score  = (float*)(w + 3817472);           // 128000 B
    int*   nms_idx    = (int*)(w + 3945472);             // 128000 B -> total 4073472 B

    hipLaunchKernelGGL(compute_keys_kernel, dim3((BATCH * (N0 + N1) + 255) / 256), dim3(256), 0, stream,
                       cls[0], cls[1], keys0, keys1);
    hipLaunchKernelGGL(radix_select_kernel, dim3(32), dim3(256), 0, stream,
                       keys0, keys1, sel_idx);
    hipLaunchKernelGGL(decode_kernel, dim3((BATCH * NTOT + 255) / 256), dim3(256), 0, stream,
                       cls[0], cls[1], cls[2], bbx[0], bbx[1], bbx[2],
                       sel_idx, boxes_all, scores_t);
    hipLaunchKernelGGL(nms_kernel, dim3(BATCH * NCLS), dim3(256), 0, stream,
                       boxes_all, scores_t, nms_score, nms_idx);
    hipLaunchKernelGGL(final_kernel, dim3(BATCH), dim3(256), 0, stream,
                       nms_score, nms_idx, boxes_all, (float*)d_out);
}